// Round 7
// baseline (492.316 us; speedup 1.0000x reference)
//
#include <hip/hip_runtime.h>
#include <stdint.h>

typedef __attribute__((ext_vector_type(8))) short bf16x8_t;  // 8 bf16 in 4 VGPRs
typedef __attribute__((ext_vector_type(4))) float f32x4_t;   // MFMA accumulator

// ---------- helpers ----------

__device__ __forceinline__ unsigned short f2bf_rn(float f) {
    unsigned int u = __float_as_uint(f);
    u += 0x7fffu + ((u >> 16) & 1u);   // round-to-nearest-even
    return (unsigned short)(u >> 16);
}

// one packed byte (as int32 in [0,256)) -> two bf16 (q-8), low nibble = even k
__device__ __forceinline__ unsigned int dq2(int v) {
    float f0 = (float)((v & 15) - 8);
    float f1 = (float)(((v >> 4) & 15) - 8);
    return (__float_as_uint(f0) >> 16) | (__float_as_uint(f1) & 0xffff0000u);
}

__device__ __forceinline__ void gload_lds16(const void* g, void* l) {
    __builtin_amdgcn_global_load_lds(
        (__attribute__((address_space(1))) void*)g,
        (__attribute__((address_space(3))) void*)l, 16, 0, 0);
}

// ---------- pre-pass kernels: emit TILED kq-major bf16 layout ----------
// Dest layout (16B chunks): [rowblk256][kt(K/64)][kq(4)][slot(512)]
//   slot = (row&255)*2 + chp,  chp = (kc&1) ^ ((row>>2)&1)   (bank swizzle)
// Each kq block (8 KB) is CONTIGUOUS -> GEMM stages it linearly via
// global_load_lds; fragment ds_reads use chp=(fq&1)^((fr>>2)&1) ->
// conflict-free (verified R2/R4/R6: SQ_LDS_BANK_CONFLICT = 0).

__device__ __forceinline__ int tiled_dest(int r, int kc, int nkt) {
    int rb = r & 255;
    int kt = kc >> 3, kcl = kc & 7;
    int kq = kcl >> 1, ch = kcl & 1;
    int chp = ch ^ ((rb >> 2) & 1);
    return ((((r >> 8) * nkt + kt) * 4 + kq) << 9) + rb * 2 + chp;
}

__global__ void cvt_x_kernel(const float4* __restrict__ x4,
                             uint4* __restrict__ o4, int nchunks, int cpr, int nkt) {
    int stride = gridDim.x * blockDim.x;
    for (int i = blockIdx.x * blockDim.x + threadIdx.x; i < nchunks; i += stride) {
        int r = i / cpr, kc = i - r * cpr;
        float4 v0 = x4[2 * i];
        float4 v1 = x4[2 * i + 1];
        uint4 o;
        o.x = (unsigned)f2bf_rn(v0.x) | ((unsigned)f2bf_rn(v0.y) << 16);
        o.y = (unsigned)f2bf_rn(v0.z) | ((unsigned)f2bf_rn(v0.w) << 16);
        o.z = (unsigned)f2bf_rn(v1.x) | ((unsigned)f2bf_rn(v1.y) << 16);
        o.w = (unsigned)f2bf_rn(v1.z) | ((unsigned)f2bf_rn(v1.w) << 16);
        o4[tiled_dest(r, kc, nkt)] = o;
    }
}

__global__ void dequant_w_kernel(const int4* __restrict__ pw4,
                                 uint4* __restrict__ o4, int nchunks, int cpr, int nkt) {
    int stride = gridDim.x * blockDim.x;
    for (int i = blockIdx.x * blockDim.x + threadIdx.x; i < nchunks; i += stride) {
        int r = i / cpr, kc = i - r * cpr;
        int4 v = pw4[i];
        uint4 o;
        o.x = dq2(v.x); o.y = dq2(v.y); o.z = dq2(v.z); o.w = dq2(v.w);
        o4[tiled_dest(r, kc, nkt)] = o;
    }
}

// ---------- main GEMM: 256x256x64, 8 waves, m201-style 4-phase/tile ----------
// Phase q of tile t: {frag ds_reads || stage 2 blocks (A,B kq=q) of t+1} ->
// [vmcnt gate at q=1,3] -> barrier -> lgkmcnt(0)+sched_barrier(0) [rule 18]
// -> setprio(1) + 16 MFMA + setprio(0) -> barrier.
// Staging block issue order per tile: [A0,B0,A1,B1,A2,B2,A3,B3] (1 per kq per
// matrix, 8 total, 2 per phase). Phases 0-1 consume kq0,1 (k-half 0);
// phases 2-3 consume kq2,3 (k-half 1).
// Gate ledger (steady state): at ph1 gate, outstanding = {A2,B2,A3,B3}(t) +
// {A0,B0,A1,B1}(t+1) = 8 -> vmcnt(4) retires t's second half (needed ph2-3).
// At ph3 gate, outstanding = 8 blocks of t+1 -> vmcnt(4) retires its first
// half (needed at t+1 ph0). Never 0 except last tile. Each gated load was
// issued >=2 phases (~1200 cyc) earlier -> latency hidden.
// WAR: block (t+1,kq) written at t.ph(kq) into buf^1; its region's last reads
// (tile t-1, k-half kq>>1) lgkm-retired before t-1.ph(2*(kq>>1)+1)'s closing
// barrier -> >=2 barriers before the write is issued.

__global__ __launch_bounds__(512, 2) void qlin_gemm256(
    const short* __restrict__ Xb, const short* __restrict__ Wb,
    const float* __restrict__ scales, const float* __restrict__ bias,
    float* __restrict__ Y, int M, int N, int K)
{
    __shared__ short As[2][4][4096];   // [buf][kq][512 slots x 8 shorts] = 64 KB
    __shared__ short Bs[2][4][4096];   // 64 KB

    int nbm = M >> 8, nbn = N >> 8, nkt = K >> 6;
    int nwg = nbm * nbn;
    // bijective XCD swizzle (m204 form)
    int bid = blockIdx.x;
    int q8 = nwg >> 3, r8 = nwg & 7;
    int xcd = bid & 7, lid = bid >> 3;
    int wgid = (xcd < r8 ? xcd * (q8 + 1) : r8 * (q8 + 1) + (xcd - r8) * q8) + lid;
    int bm = wgid % nbm, bn = wgid / nbm;

    const short* ga = Xb + (size_t)bm * nkt * 16384;
    const short* gb = Wb + (size_t)bn * nkt * 16384;

    int tid = threadIdx.x, lane = tid & 63, wid = tid >> 6;
    int wr = wid >> 2, wc = wid & 3;          // 2x4 wave grid, per-wave out 128x64
    int fr = lane & 15, fq = lane >> 4;       // frag row / k-subchunk
    int chp = (fq & 1) ^ ((fr >> 2) & 1);     // lane-constant chunk swizzle

    f32x4_t acc[8][4] = {};

    int lsel = (fq >> 1) * 4096 + fr * 16 + chp * 8;
    int arow = wr * 2048;                     // (wr*128 rows)*16 shorts
    int brow = wc * 1024;                     // (wc*64 rows)*16 shorts

#define STAGE1(base_, b_, kq_)                                                \
    do {                                                                      \
        gload_lds16(ga + (base_) + (kq_) * 4096 + tid * 8,                    \
                    &As[b_][kq_][wid * 512]);                                 \
        gload_lds16(gb + (base_) + (kq_) * 4096 + tid * 8,                    \
                    &Bs[b_][kq_][wid * 512]);                                 \
    } while (0)

#define FRAG_B(h_)                                                            \
    _Pragma("unroll")                                                         \
    for (int n = 0; n < 4; ++n)                                               \
        bfrag[n] = *(const bf16x8_t*)&Bb[(h_) * 8192 + lsel + brow + n * 256];

#define FRAG_A(h_, mb_)                                                       \
    _Pragma("unroll")                                                         \
    for (int mi = 0; mi < 4; ++mi)                                            \
        afrag[mi] = *(const bf16x8_t*)&Ab[(h_) * 8192 + lsel + arow +         \
                                          ((mb_) + mi) * 256];

#define MFMA16(mb_)                                                           \
    __builtin_amdgcn_s_setprio(1);                                            \
    _Pragma("unroll")                                                         \
    for (int mi = 0; mi < 4; ++mi)                                            \
        _Pragma("unroll")                                                     \
        for (int n = 0; n < 4; ++n)                                           \
            acc[(mb_) + mi][n] = __builtin_amdgcn_mfma_f32_16x16x32_bf16(     \
                afrag[mi], bfrag[n], acc[(mb_) + mi][n], 0, 0, 0);            \
    __builtin_amdgcn_s_setprio(0);

#define BAR1_LGKM                                                             \
    __builtin_amdgcn_s_barrier();                                             \
    asm volatile("s_waitcnt lgkmcnt(0)" ::: "memory");                        \
    __builtin_amdgcn_sched_barrier(0);

#define BAR2                                                                  \
    __builtin_amdgcn_s_barrier();                                             \
    __builtin_amdgcn_sched_barrier(0);

    // prologue: stage tile 0 (order A0,B0,A1,B1,A2,B2,A3,B3), gate first half
    #pragma unroll
    for (int kq = 0; kq < 4; ++kq) STAGE1((size_t)0, 0, kq);
    asm volatile("s_waitcnt vmcnt(4)" ::: "memory");
    __builtin_amdgcn_s_barrier();
    __builtin_amdgcn_sched_barrier(0);

    int nt = nkt;
    for (int t = 0; t < nt; ++t) {
        const short* Ab = &As[t & 1][0][0];
        const short* Bb = &Bs[t & 1][0][0];
        const bool st = (t + 1 < nt);
        const size_t nbase = (size_t)(t + 1) * 16384;
        const int nb = (t + 1) & 1;
        bf16x8_t bfrag[4], afrag[4];

        // ---- phase 0: k-half 0, m 0..3 ----
        FRAG_B(0)
        FRAG_A(0, 0)
        if (st) STAGE1(nbase, nb, 0);
        BAR1_LGKM
        MFMA16(0)
        BAR2

        // ---- phase 1: k-half 0, m 4..7 ----
        FRAG_A(0, 4)
        if (st) {
            STAGE1(nbase, nb, 1);
            asm volatile("s_waitcnt vmcnt(4)" ::: "memory");
        } else {
            asm volatile("s_waitcnt vmcnt(0)" ::: "memory");
        }
        BAR1_LGKM
        MFMA16(4)
        BAR2

        // ---- phase 2: k-half 1, m 0..3 ----
        FRAG_B(1)
        FRAG_A(1, 0)
        if (st) STAGE1(nbase, nb, 2);
        BAR1_LGKM
        MFMA16(0)
        BAR2

        // ---- phase 3: k-half 1, m 4..7 ----
        FRAG_A(1, 4)
        if (st) {
            STAGE1(nbase, nb, 3);
            asm volatile("s_waitcnt vmcnt(4)" ::: "memory");
        } else {
            asm volatile("s_waitcnt vmcnt(0)" ::: "memory");
        }
        BAR1_LGKM
        MFMA16(4)
        BAR2
    }
#undef STAGE1
#undef FRAG_B
#undef FRAG_A
#undef MFMA16
#undef BAR1_LGKM
#undef BAR2

    int row_base = bm * 256 + wr * 128;
    int col_base = bn * 256 + wc * 64;
    #pragma unroll
    for (int n = 0; n < 4; ++n) {
        int col = col_base + n * 16 + fr;
        float sc = scales[col], bi = bias[col];
        #pragma unroll
        for (int m = 0; m < 8; ++m) {
            int m0 = row_base + m * 16 + fq * 4;
            #pragma unroll
            for (int r2 = 0; r2 < 4; ++r2)
                Y[(size_t)(m0 + r2) * N + col] = acc[m][n][r2] * sc + bi;
        }
    }
}

// ---------- fallback (if ws too small / odd dims): tiled fp32, inline dequant --

__global__ __launch_bounds__(256) void qlin_fallback(
    const float* __restrict__ x, const int* __restrict__ pw,
    const float* __restrict__ scales, const float* __restrict__ bias,
    float* __restrict__ Y, int M, int N, int K)
{
    __shared__ float Xs[64][32];
    __shared__ float Ws[64][33];
    int bn = blockIdx.x, bm = blockIdx.y;
    int tid = threadIdx.x;
    int tr = tid >> 4, tc = tid & 15;
    float acc[4][4] = {};
    int K2 = K >> 1;
    for (int kt = 0; kt < K; kt += 32) {
        #pragma unroll
        for (int u = 0; u < 8; ++u) {
            int idx = u * 256 + tid;
            int rr = idx >> 5, cc = idx & 31;
            Xs[rr][cc] = x[(size_t)(bm * 64 + rr) * K + kt + cc];
        }
        #pragma unroll
        for (int u = 0; u < 4; ++u) {
            int idx = u * 256 + tid;
            int rr = idx >> 4, cc = idx & 15;
            int v = pw[(size_t)(bn * 64 + rr) * K2 + (kt >> 1) + cc];
            Ws[rr][cc * 2]     = (float)((v & 15) - 8);
            Ws[rr][cc * 2 + 1] = (float)(((v >> 4) & 15) - 8);
        }
        __syncthreads();
        #pragma unroll 8
        for (int kk = 0; kk < 32; ++kk) {
            float xv[4], wv[4];
            #pragma unroll
            for (int i = 0; i < 4; ++i) xv[i] = Xs[tr * 4 + i][kk];
            #pragma unroll
            for (int j = 0; j < 4; ++j) wv[j] = Ws[tc * 4 + j][kk];
            #pragma unroll
            for (int i = 0; i < 4; ++i)
                #pragma unroll
                for (int j = 0; j < 4; ++j)
                    acc[i][j] += xv[i] * wv[j];
        }
        __syncthreads();
    }
    #pragma unroll
    for (int j = 0; j < 4; ++j) {
        int n = bn * 64 + tc * 4 + j;
        float sc = scales[n], bi = bias[n];
        #pragma unroll
        for (int i = 0; i < 4; ++i) {
            int m = bm * 64 + tr * 4 + i;
            Y[(size_t)m * N + n] = acc[i][j] * sc + bi;
        }
    }
}

// ---------- host ----------

extern "C" void kernel_launch(void* const* d_in, const int* in_sizes, int n_in,
                              void* d_out, int out_size, void* d_ws, size_t ws_size,
                              hipStream_t stream) {
    const float* x      = (const float*)d_in[0];
    const int*   pw     = (const int*)d_in[1];
    const float* scales = (const float*)d_in[2];
    const float* bias   = (const float*)d_in[3];
    float*       y      = (float*)d_out;

    int N = in_sizes[2];                         // 11008
    long long pwe = in_sizes[1];                 // N*K/2
    int K = (int)((2 * pwe) / N);                // 4096
    int M = in_sizes[0] / K;                     // 4096

    size_t xb_bytes = (size_t)M * K * 2;
    size_t wb_bytes = (size_t)N * K * 2;

    bool fits = (ws_size >= xb_bytes + wb_bytes);
    bool dims_ok = (M % 256 == 0) && (N % 256 == 0) && (K % 64 == 0) && (K >= 128);

    if (fits && dims_ok) {
        short* xb = (short*)d_ws;
        short* wb = (short*)((char*)d_ws + xb_bytes);
        int cpr = K / 8;                         // 16B chunks per row
        int nkt = K / 64;
        int ncx = (int)((size_t)M * K / 8);
        hipLaunchKernelGGL(cvt_x_kernel, dim3(2048), dim3(256), 0, stream,
                           (const float4*)x, (uint4*)xb, ncx, cpr, nkt);
        int ncw = (int)(pwe / 4);                // = N*K/8
        hipLaunchKernelGGL(dequant_w_kernel, dim3(2048), dim3(256), 0, stream,
                           (const int4*)pw, (uint4*)wb, ncw, cpr, nkt);
        int nwg = (M / 256) * (N / 256);
        hipLaunchKernelGGL(qlin_gemm256, dim3(nwg), dim3(512), 0, stream,
                           xb, wb, scales, bias, y, M, N, K);
    } else {
        hipLaunchKernelGGL(qlin_fallback, dim3(N / 64, M / 64), dim3(256), 0, stream,
                           x, pw, scales, bias, y, M, N, K);
    }
}